// Round 9
// baseline (370.730 us; speedup 1.0000x reference)
//
#include <hip/hip_runtime.h>
#include <math.h>

// Problem constants
#define NB   4
#define SEQ  2048
#define NH   12
#define CIN  2304      // 3*768 floats per token
#define TM   64        // kv rows per chunk
#define NCH  (SEQ/TM)  // 32 chunks
#define TQ   128       // q rows per block (8 waves x 16 q)

typedef _Float16 half8 __attribute__((ext_vector_type(8)));
typedef _Float16 half4 __attribute__((ext_vector_type(4)));
typedef float    f32x4 __attribute__((ext_vector_type(4)));

// R8 post-mortem: dbuf didn't help (184->202us) -> barriers were never the
// limiter; 3 waves/SIMD can't hide per-wave dependency chains (VALU 37%,
// MFMA 10%, all idle). R7 proved more BLOCKS blows per-XCD L2. This round:
// more WAVES PER BLOCK. Same 768-block grid / TQ=128 / 16 sharers / XCD
// swizzle / dbuf, but 512-thread blocks (8 waves x one 16-q strip each) ->
// 24 waves/CU = 6 waves/SIMD, 2x latency hiding, identical L2 traffic.
// Staging splits 8 ways: K 8 rows/wave (8-lane LN reduce), V 8 kv/wave.
__global__ __launch_bounds__(512, 6)
void fused_ln_attn(const float* __restrict__ QKV,
                   const float* __restrict__ q_scale,
                   const float* __restrict__ q_bias,
                   const float* __restrict__ k_scale,
                   const float* __restrict__ k_bias,
                   float* __restrict__ out)
{
    // dbuf 2 x (Ka 8K | Vt 8K) = 32 KB, Qt/P 16 KB  -> 48 KB, 3 blocks/CU
    __shared__ __align__(16) unsigned char sm[49152];
    unsigned char* Qt = sm + 32768;        // 128 rows x 128 B

    const int tid  = threadIdx.x;
    const int L    = tid & 63;
    const int wv   = tid >> 6;   // 0..7
    const int n16  = L & 15;
    const int quad = L >> 4;
    const int sw   = n16 & 7;   // row-swizzle key for fragment reads
    const int r4   = L >> 2;    // Q staging: row within 16
    const int c4   = L & 3;     // Q staging: 16-float column group
    const int r8   = L >> 3;    // K staging: row within 8
    const int c8   = L & 7;     // K staging: 8-float column group

    // XCD swizzle (R6-validated): all 16 q-tiles of one (b,h) share id%8
    const int id  = blockIdx.x;
    const int xcd = id & 7;
    const int qt  = (id >> 3) & 15;
    const int grp = id >> 7;          // 0..5
    const int bh  = grp * 8 + xcd;    // 0..47
    const int b   = bh / NH;
    const int h   = bh - b * NH;
    const int q0  = qt * TQ;

    const float4* QKV4 = (const float4*)QKV;
    unsigned char* Pw = Qt + wv * 2048;   // wave-private P strip (16 q x 128 B)

    // K scale/bias for this lane's 8 d-columns (c8*8 .. +7)
    float4 ksr[2], kbr[2];
    #pragma unroll
    for (int i = 0; i < 2; ++i) {
        ksr[i] = ((const float4*)k_scale)[c8 * 2 + i];
        kbr[i] = ((const float4*)k_bias)[c8 * 2 + i];
    }

    // ---- register prefetch of chunk K/V ----
    // K: wave covers rows [wv*8, wv*8+8), lane: row wv*8+r8, floats [c8*8,+8)
    // V: lane L = d, kv rows [wv*8, wv*8+8)
    float4 kx[2];
    float  vv[8];
    #define PREFETCH(MC)                                                          \
    {                                                                             \
        const size_t kb4 = (size_t)(b*SEQ + (MC)*64 + wv*8 + r8) * 576 + 192 + h*16 + c8*2; \
        kx[0] = QKV4[kb4];                                                        \
        kx[1] = QKV4[kb4 + 1];                                                    \
        const float* gv = QKV + (size_t)(b*SEQ + (MC)*64 + wv*8) * CIN + 1536 + h*64 + L; \
        _Pragma("unroll")                                                         \
        for (int j = 0; j < 8; ++j) vv[j] = gv[(size_t)j * CIN];                  \
    }

    // ---- stage prefetched regs into swizzled tile images in buf P ----
    #define STAGE(P)                                                              \
    {                                                                             \
        unsigned char* Ka_ = sm + (P)*16384;                                      \
        unsigned char* Vt_ = Ka_ + 8192;                                          \
        const int row = wv*8 + r8;                                                \
        float s = 0.f, s2 = 0.f;                                                  \
        _Pragma("unroll")                                                         \
        for (int i = 0; i < 2; ++i) {                                             \
            s  += kx[i].x + kx[i].y + kx[i].z + kx[i].w;                          \
            s2 += kx[i].x*kx[i].x + kx[i].y*kx[i].y + kx[i].z*kx[i].z + kx[i].w*kx[i].w; \
        }                                                                         \
        s  += __shfl_xor(s, 1);  s  += __shfl_xor(s, 2);  s  += __shfl_xor(s, 4); \
        s2 += __shfl_xor(s2, 1); s2 += __shfl_xor(s2, 2); s2 += __shfl_xor(s2, 4);\
        float mu = s * 0.015625f;                                                 \
        float rstd = rsqrtf(s2 * 0.015625f - mu*mu + 1e-6f);                      \
        float nb0 = -mu * rstd;                                                   \
        half8 h0;                                                                 \
        _Pragma("unroll")                                                         \
        for (int i = 0; i < 2; ++i) {                                             \
            float e0 = fmaf(kx[i].x, rstd, nb0) * ksr[i].x + kbr[i].x;            \
            float e1 = fmaf(kx[i].y, rstd, nb0) * ksr[i].y + kbr[i].y;            \
            float e2 = fmaf(kx[i].z, rstd, nb0) * ksr[i].z + kbr[i].z;            \
            float e3 = fmaf(kx[i].w, rstd, nb0) * ksr[i].w + kbr[i].w;            \
            h0[i*4+0]=(_Float16)e0; h0[i*4+1]=(_Float16)e1;                       \
            h0[i*4+2]=(_Float16)e2; h0[i*4+3]=(_Float16)e3;                       \
        }                                                                         \
        *(half8*)(Ka_ + row*128 + ((c8 ^ (row & 7)) * 16)) = h0;                  \
        half8 a0;                                                                 \
        _Pragma("unroll")                                                         \
        for (int j = 0; j < 8; ++j) a0[j] = (_Float16)vv[j];                      \
        *(half8*)(Vt_ + L*128 + ((wv ^ (L & 7)) * 16)) = a0;                      \
    }

    PREFETCH(0)

    // ---- Q prologue: LN 16 rows/wave, fold 0.125*log2(e), swizzle into Qt ----
    {
        const float SC = 0.125f * 1.44269504088896340736f;
        const int row = wv*16 + r4;            // 0..127
        const size_t base4 = (size_t)(b*SEQ + q0 + row) * 576 + h*16 + c4*4;
        float4 x[4];
        #pragma unroll
        for (int i = 0; i < 4; ++i) x[i] = QKV4[base4 + i];
        float s = 0.f, s2 = 0.f;
        #pragma unroll
        for (int i = 0; i < 4; ++i) {
            s  += x[i].x + x[i].y + x[i].z + x[i].w;
            s2 += x[i].x*x[i].x + x[i].y*x[i].y + x[i].z*x[i].z + x[i].w*x[i].w;
        }
        s  += __shfl_xor(s, 1);  s  += __shfl_xor(s, 2);
        s2 += __shfl_xor(s2, 1); s2 += __shfl_xor(s2, 2);
        float mu = s * 0.015625f;
        float rstd = rsqrtf(s2 * 0.015625f - mu*mu + 1e-6f);
        float nb0 = -mu * rstd;
        half8 h0, h1;
        #pragma unroll
        for (int i = 0; i < 4; ++i) {
            float4 sc = ((const float4*)q_scale)[c4*4 + i];
            float4 bi = ((const float4*)q_bias)[c4*4 + i];
            float e0 = (fmaf(x[i].x, rstd, nb0) * sc.x + bi.x) * SC;
            float e1 = (fmaf(x[i].y, rstd, nb0) * sc.y + bi.y) * SC;
            float e2 = (fmaf(x[i].z, rstd, nb0) * sc.z + bi.z) * SC;
            float e3 = (fmaf(x[i].w, rstd, nb0) * sc.w + bi.w) * SC;
            if (i < 2) { h0[i*4+0]=(_Float16)e0; h0[i*4+1]=(_Float16)e1; h0[i*4+2]=(_Float16)e2; h0[i*4+3]=(_Float16)e3; }
            else { int j=(i-2)*4; h1[j+0]=(_Float16)e0; h1[j+1]=(_Float16)e1; h1[j+2]=(_Float16)e2; h1[j+3]=(_Float16)e3; }
        }
        *(half8*)(Qt + row*128 + (((2*c4+0) ^ (r4 & 7)) * 16)) = h0;
        *(half8*)(Qt + row*128 + (((2*c4+1) ^ (r4 & 7)) * 16)) = h1;
    }

    // Q fragments to registers (wave-private rows; same-wave DS is ordered)
    half8 qf[2];
    {
        const unsigned char* qrow = Qt + (wv*16 + n16)*128;
        #pragma unroll
        for (int ks = 0; ks < 2; ++ks)
            qf[ks] = *(const half8*)(qrow + (((quad + 4*ks) ^ sw) * 16));
    }

    // stage chunk 0 into buf0, prefetch chunk 1, single barrier
    STAGE(0)
    PREFETCH(1)
    __syncthreads();

    f32x4 oacc[4] = {};
    float lsum = 0.f;

    for (int mc = 0; mc < NCH; ++mc) {
        const int p = mc & 1;

        // stage chunk mc+1 into the other buffer (regs hold chunk mc+1)
        if (mc + 1 < NCH) STAGE(p ^ 1)
        // prefetch chunk mc+2 into regs (has a full iteration to land)
        if (mc + 2 < NCH) PREFETCH(mc + 2)

        const unsigned char* Ka = sm + p*16384;
        const unsigned char* Vt = Ka + 8192;

        // ---- S^T = K x Q^T : 8 MFMAs ----
        f32x4 sacc[4] = {};
        #pragma unroll
        for (int ks = 0; ks < 2; ++ks) {
            #pragma unroll
            for (int mt = 0; mt < 4; ++mt) {
                half8 ak = *(const half8*)(Ka + (16*mt + n16)*128 + (((quad + 4*ks) ^ sw) * 16));
                sacc[mt] = __builtin_amdgcn_mfma_f32_16x16x32_f16(ak, qf[ks], sacc[mt], 0, 0, 0);
            }
        }

        // ---- softmax: p = exp2(s) (log2e folded into Q); no max shift ----
        {
            float ls = 0.f;
            #pragma unroll
            for (int mt = 0; mt < 4; ++mt) {
                float p0 = __builtin_exp2f(sacc[mt][0]);
                float p1 = __builtin_exp2f(sacc[mt][1]);
                float p2 = __builtin_exp2f(sacc[mt][2]);
                float p3 = __builtin_exp2f(sacc[mt][3]);
                ls += (p0 + p1) + (p2 + p3);
                half4 hp; hp[0]=(_Float16)p0; hp[1]=(_Float16)p1; hp[2]=(_Float16)p2; hp[3]=(_Float16)p3;
                *(half4*)(Pw + n16*128 + (((4*mt + quad) ^ n16) * 8)) = hp;
            }
            ls += __shfl_xor(ls, 16);
            ls += __shfl_xor(ls, 32);
            lsum += ls;
        }

        // ---- O^T += Vt x P : 8 MFMAs (P wave-private: no barrier) ----
        #pragma unroll
        for (int ks = 0; ks < 2; ++ks) {
            half4 b0 = *(const half4*)(Pw + n16*128 + (((8*ks + 2*quad + 0) ^ n16) * 8));
            half4 b1 = *(const half4*)(Pw + n16*128 + (((8*ks + 2*quad + 1) ^ n16) * 8));
            half8 bp;
            #pragma unroll
            for (int j = 0; j < 4; ++j) { bp[j] = b0[j]; bp[4+j] = b1[j]; }
            #pragma unroll
            for (int mt = 0; mt < 4; ++mt) {
                half8 av = *(const half8*)(Vt + (16*mt + n16)*128 + (((quad + 4*ks) ^ sw) * 16));
                oacc[mt] = __builtin_amdgcn_mfma_f32_16x16x32_f16(av, bp, oacc[mt], 0, 0, 0);
            }
        }

        __syncthreads();   // buf[p^1] staged by all; buf[p] reads done
    }

    // ---- epilogue: lane owns q = q0 + wv*16 + n16, d = 16mt + 4quad + r ----
    float inv = 1.0f / lsum;
    float4* out4 = (float4*)out;
    size_t rowb = ((size_t)(b*NH + h)*SEQ + q0 + wv*16 + n16) * 16;
    #pragma unroll
    for (int mt = 0; mt < 4; ++mt)
        out4[rowb + mt*4 + quad] = make_float4(oacc[mt][0]*inv, oacc[mt][1]*inv,
                                               oacc[mt][2]*inv, oacc[mt][3]*inv);
}

extern "C" void kernel_launch(void* const* d_in, const int* in_sizes, int n_in,
                              void* d_out, int out_size, void* d_ws, size_t ws_size,
                              hipStream_t stream) {
    const float* QKV     = (const float*)d_in[0];
    const float* q_scale = (const float*)d_in[1];
    const float* q_bias  = (const float*)d_in[2];
    const float* k_scale = (const float*)d_in[3];
    const float* k_bias  = (const float*)d_in[4];
    float* out = (float*)d_out;

    // flat 768-block grid (512 thr), decoded inside for XCD-locality
    fused_ln_attn<<<dim3(NB * NH * (SEQ / TQ)), 512, 0, stream>>>(
        QKV, q_scale, q_bias, k_scale, k_bias, out);
}

// Round 10
// 209.862 us; speedup vs baseline: 1.7665x; 1.7665x over previous
//
#include <hip/hip_runtime.h>
#include <math.h>

// Problem constants
#define NB   4
#define SEQ  2048
#define NH   12
#define CIN  2304      // 3*768 floats per token
#define TM   64        // kv rows per chunk
#define NCH  (SEQ/TM)  // 32 chunks
#define TQ   128       // q rows per block (4 waves x 32 q)

typedef _Float16 half8 __attribute__((ext_vector_type(8)));
typedef _Float16 half4 __attribute__((ext_vector_type(4)));
typedef float    f32x4 __attribute__((ext_vector_type(4)));
typedef unsigned int u32;
#define AS1 __attribute__((address_space(1)))
#define AS3 __attribute__((address_space(3)))

// K/V tile = 64x64 f16 = 8192 B stored as the EXACT swizzled LDS image
// (row r * 128 B, 16B-group g at g ^ (r&7)) so attention can DMA verbatim
// with global_load_lds and all ds_read_b128 fragments stay conflict-free.
#define TILE_B  8192
#define KT_BYTES ((size_t)NB*NH*NCH*TILE_B)   // 12,582,912 (K tiles)
#define WS_FULL  (2*KT_BYTES)                 // 25,165,824 (K+V tiles)

static __device__ __forceinline__ int dec_xcd(int id, int& b, int& h, int& q0) {
    // XCD swizzle (R6-validated): all 16 q-tiles of one (b,h) share id%8
    const int xcd = id & 7;
    const int qt  = (id >> 3) & 15;
    const int grp = id >> 7;          // 0..5
    const int bh  = grp * 8 + xcd;    // 0..47
    b = bh / NH; h = bh - b * NH; q0 = qt * TQ;
    return bh;
}

// ---------------------------------------------------------------------------
// Preprocess: LayerNorm K into swizzled f16 tiles (always); V transposed
// tiles too when writeV!=0. Grid (mc,h,b)=(32,12,4), 256 thr.  (R3-validated)
// ---------------------------------------------------------------------------
__global__ __launch_bounds__(256, 4)
void preprocess_kernel(const float* __restrict__ QKV,
                       const float* __restrict__ k_scale,
                       const float* __restrict__ k_bias,
                       unsigned char* __restrict__ ws, int writeV)
{
    const int tid = threadIdx.x;
    const int L   = tid & 63;
    const int wv  = tid >> 6;
    const int r4  = L >> 2;
    const int c4  = L & 3;
    const int mc  = blockIdx.x, h = blockIdx.y, b = blockIdx.z;

    unsigned char* Kt = ws + (size_t)((b*NH + h)*NCH + mc) * TILE_B;

    const float4* QKV4 = (const float4*)QKV;
    const int row = wv*16 + r4;
    const size_t base4 = (size_t)(b*SEQ + mc*64 + row) * 576 + h*16 + c4*4;

    {   // K: LN -> swizzled tile image
        float4 x[4];
        #pragma unroll
        for (int i = 0; i < 4; ++i) x[i] = QKV4[base4 + 192 + i];
        float s = 0.f, s2 = 0.f;
        #pragma unroll
        for (int i = 0; i < 4; ++i) {
            s  += x[i].x + x[i].y + x[i].z + x[i].w;
            s2 += x[i].x*x[i].x + x[i].y*x[i].y + x[i].z*x[i].z + x[i].w*x[i].w;
        }
        s  += __shfl_xor(s, 1);  s  += __shfl_xor(s, 2);
        s2 += __shfl_xor(s2, 1); s2 += __shfl_xor(s2, 2);
        float mu = s * 0.015625f;
        float rstd = rsqrtf(s2 * 0.015625f - mu*mu + 1e-6f);
        float nb0 = -mu * rstd;
        half8 h0, h1;
        #pragma unroll
        for (int i = 0; i < 4; ++i) {
            float4 sc = ((const float4*)k_scale)[c4*4 + i];
            float4 bi = ((const float4*)k_bias)[c4*4 + i];
            float e0 = fmaf(x[i].x, rstd, nb0) * sc.x + bi.x;
            float e1 = fmaf(x[i].y, rstd, nb0) * sc.y + bi.y;
            float e2 = fmaf(x[i].z, rstd, nb0) * sc.z + bi.z;
            float e3 = fmaf(x[i].w, rstd, nb0) * sc.w + bi.w;
            if (i < 2) { h0[i*4+0]=(_Float16)e0; h0[i*4+1]=(_Float16)e1; h0[i*4+2]=(_Float16)e2; h0[i*4+3]=(_Float16)e3; }
            else { int j=(i-2)*4; h1[j+0]=(_Float16)e0; h1[j+1]=(_Float16)e1; h1[j+2]=(_Float16)e2; h1[j+3]=(_Float16)e3; }
        }
        *(half8*)(Kt + row*128 + (((2*c4+0) ^ (row & 7)) * 16)) = h0;
        *(half8*)(Kt + row*128 + (((2*c4+1) ^ (row & 7)) * 16)) = h1;
    }

    if (writeV) {   // V: transpose -> swizzled tile (lane = d)
        unsigned char* Vt = ws + KT_BYTES + (size_t)((b*NH + h)*NCH + mc) * TILE_B;
        const float* gv = QKV + (size_t)(b*SEQ + mc*64 + wv*16)*CIN + 1536 + h*64 + L;
        float vvp[16];
        #pragma unroll
        for (int j = 0; j < 16; ++j) vvp[j] = gv[(size_t)j * CIN];
        half8 a0, a1;
        #pragma unroll
        for (int j = 0; j < 8; ++j) { a0[j] = (_Float16)vvp[j]; a1[j] = (_Float16)vvp[j+8]; }
        *(half8*)(Vt + L*128 + (((2*wv+0) ^ (L & 7)) * 16)) = a0;
        *(half8*)(Vt + L*128 + (((2*wv+1) ^ (L & 7)) * 16)) = a1;
    }
}

// Shared Q-prologue + fragment pickup (R6-validated), emitted inline.
#define Q_PROLOGUE(QTBASE)                                                        \
    const float SC = 0.125f * 1.44269504088896340736f;                            \
    _Pragma("unroll")                                                             \
    for (int g = 0; g < 2; ++g) {                                                 \
        const int row = wv*32 + g*16 + r4;                                        \
        const size_t base4 = (size_t)(b*SEQ + q0 + row) * 576 + h*16 + c4*4;      \
        float4 x[4];                                                              \
        _Pragma("unroll")                                                         \
        for (int i = 0; i < 4; ++i) x[i] = QKV4[base4 + i];                       \
        float s = 0.f, s2 = 0.f;                                                  \
        _Pragma("unroll")                                                         \
        for (int i = 0; i < 4; ++i) {                                             \
            s  += x[i].x + x[i].y + x[i].z + x[i].w;                              \
            s2 += x[i].x*x[i].x + x[i].y*x[i].y + x[i].z*x[i].z + x[i].w*x[i].w;  \
        }                                                                         \
        s  += __shfl_xor(s, 1);  s  += __shfl_xor(s, 2);                          \
        s2 += __shfl_xor(s2, 1); s2 += __shfl_xor(s2, 2);                         \
        float mu = s * 0.015625f;                                                 \
        float rstd = rsqrtf(s2 * 0.015625f - mu*mu + 1e-6f);                      \
        float nb0 = -mu * rstd;                                                   \
        half8 h0, h1;                                                             \
        _Pragma("unroll")                                                         \
        for (int i = 0; i < 4; ++i) {                                             \
            float4 sc = ((const float4*)q_scale)[c4*4 + i];                       \
            float4 bi = ((const float4*)q_bias)[c4*4 + i];                        \
            float e0 = (fmaf(x[i].x, rstd, nb0) * sc.x + bi.x) * SC;              \
            float e1 = (fmaf(x[i].y, rstd, nb0) * sc.y + bi.y) * SC;              \
            float e2 = (fmaf(x[i].z, rstd, nb0) * sc.z + bi.z) * SC;              \
            float e3 = (fmaf(x[i].w, rstd, nb0) * sc.w + bi.w) * SC;              \
            if (i < 2) { h0[i*4+0]=(_Float16)e0; h0[i*4+1]=(_Float16)e1; h0[i*4+2]=(_Float16)e2; h0[i*4+3]=(_Float16)e3; } \
            else { int j=(i-2)*4; h1[j+0]=(_Float16)e0; h1[j+1]=(_Float16)e1; h1[j+2]=(_Float16)e2; h1[j+3]=(_Float16)e3; } \
        }                                                                         \
        *(half8*)((QTBASE) + row*128 + (((2*c4+0) ^ (r4 & 7)) * 16)) = h0;        \
        *(half8*)((QTBASE) + row*128 + (((2*c4+1) ^ (r4 & 7)) * 16)) = h1;        \
    }                                                                             \
    half8 qf[2][2];                                                               \
    _Pragma("unroll")                                                             \
    for (int s = 0; s < 2; ++s) {                                                 \
        const unsigned char* qrow = (QTBASE) + (wv*32 + s*16 + n16)*128;          \
        _Pragma("unroll")                                                         \
        for (int ks = 0; ks < 2; ++ks)                                            \
            qf[s][ks] = *(const half8*)(qrow + (((quad + 4*ks) ^ sw) * 16));      \
    }

// Compute body for one chunk given Ka/Vt base pointers (R6-validated).
#define CHUNK_COMPUTE(KAB, VTB)                                                   \
    {                                                                             \
        f32x4 sacc[2][4] = {};                                                    \
        _Pragma("unroll")                                                         \
        for (int ks = 0; ks < 2; ++ks) {                                          \
            half8 ak[4];                                                          \
            _Pragma("unroll")                                                     \
            for (int mt = 0; mt < 4; ++mt)                                        \
                ak[mt] = *(const half8*)((KAB) + (16*mt + n16)*128 + (((quad + 4*ks) ^ sw) * 16)); \
            _Pragma("unroll")                                                     \
            for (int s = 0; s < 2; ++s)                                           \
                _Pragma("unroll")                                                 \
                for (int mt = 0; mt < 4; ++mt)                                    \
                    sacc[s][mt] = __builtin_amdgcn_mfma_f32_16x16x32_f16(ak[mt], qf[s][ks], sacc[s][mt], 0, 0, 0); \
        }                                                                         \
        _Pragma("unroll")                                                         \
        for (int s = 0; s < 2; ++s) {                                             \
            float ls = 0.f;                                                       \
            _Pragma("unroll")                                                     \
            for (int mt = 0; mt < 4; ++mt) {                                      \
                float p0 = __builtin_exp2f(sacc[s][mt][0]);                       \
                float p1 = __builtin_exp2f(sacc[s][mt][1]);                       \
                float p2 = __builtin_exp2f(sacc[s][mt][2]);                       \
                float p3 = __builtin_exp2f(sacc[s][mt][3]);                       \
                ls += (p0 + p1) + (p2 + p3);                                      \
                half4 hp; hp[0]=(_Float16)p0; hp[1]=(_Float16)p1; hp[2]=(_Float16)p2; hp[3]=(_Float16)p3; \
                *(half4*)(Pw + s*2048 + n16*128 + (((4*mt + quad) ^ n16) * 8)) = hp; \
            }                                                                     \
            ls += __shfl_xor(ls, 16);                                             \
            ls += __shfl_xor(ls, 32);                                             \
            lsum[s] += ls;                                                        \
        }                                                                         \
        _Pragma("unroll")                                                         \
        for (int ks = 0; ks < 2; ++ks) {                                          \
            half8 av[4];                                                          \
            _Pragma("unroll")                                                     \
            for (int mt = 0; mt < 4; ++mt)                                        \
                av[mt] = *(const half8*)((VTB) + (16*mt + n16)*128 + (((quad + 4*ks) ^ sw) * 16)); \
            _Pragma("unroll")                                                     \
            for (int s = 0; s < 2; ++s) {                                         \
                half4 b0 = *(const half4*)(Pw + s*2048 + n16*128 + (((8*ks + 2*quad + 0) ^ n16) * 8)); \
                half4 b1 = *(const half4*)(Pw + s*2048 + n16*128 + (((8*ks + 2*quad + 1) ^ n16) * 8)); \
                half8 bp;                                                         \
                _Pragma("unroll")                                                 \
                for (int j = 0; j < 4; ++j) { bp[j] = b0[j]; bp[4+j] = b1[j]; }   \
                _Pragma("unroll")                                                 \
                for (int mt = 0; mt < 4; ++mt)                                    \
                    oacc[s][mt] = __builtin_amdgcn_mfma_f32_16x16x32_f16(av[mt], bp, oacc[s][mt], 0, 0, 0); \
            }                                                                     \
        }                                                                         \
    }

#define EPILOGUE()                                                                \
    {                                                                             \
        float4* out4 = (float4*)out;                                              \
        _Pragma("unroll")                                                         \
        for (int s = 0; s < 2; ++s) {                                             \
            float inv = 1.0f / lsum[s];                                           \
            size_t rowb = ((size_t)(b*NH + h)*SEQ + q0 + wv*32 + s*16 + n16) * 16;\
            _Pragma("unroll")                                                     \
            for (int mt = 0; mt < 4; ++mt)                                        \
                out4[rowb + mt*4 + quad] = make_float4(oacc[s][mt][0]*inv, oacc[s][mt][1]*inv, oacc[s][mt][2]*inv, oacc[s][mt][3]*inv); \
        }                                                                         \
    }

#define COMMON_IDS()                                                              \
    const int tid  = threadIdx.x;                                                 \
    const int L    = tid & 63;                                                    \
    const int wv   = tid >> 6;                                                    \
    const int n16  = L & 15;                                                      \
    const int quad = L >> 4;                                                      \
    const int sw   = n16 & 7;                                                     \
    const int r4   = L >> 2;                                                      \
    const int c4   = L & 3;                                                       \
    int b, h, q0; dec_xcd(blockIdx.x, b, h, q0);                                  \
    const float4* QKV4 = (const float4*)QKV;

// ---------------------------------------------------------------------------
// Tier (a): both K and V tiles DMA'd, double-buffered, 1 barrier/chunk.
// ---------------------------------------------------------------------------
__global__ __launch_bounds__(256, 3)
void attn_full(const float* __restrict__ QKV,
               const float* __restrict__ q_scale,
               const float* __restrict__ q_bias,
               const unsigned char* __restrict__ ws,
               float* __restrict__ out)
{
    __shared__ __align__(16) unsigned char sm[49152]; // 2x(Ka8K|Vt8K) + Qt/P 16K
    COMMON_IDS()
    unsigned char* Qt = sm + 32768;
    unsigned char* Pw = Qt + wv*4096;

    const unsigned char* Ktiles = ws + (size_t)((b*NH + h)*NCH) * TILE_B;
    const unsigned char* Vtiles = ws + KT_BYTES + (size_t)((b*NH + h)*NCH) * TILE_B;

    #define ISSUE_KV(MC, P)                                                       \
    {                                                                             \
        const unsigned char* kt_ = Ktiles + (size_t)(MC) * TILE_B;                \
        const unsigned char* vt_ = Vtiles + (size_t)(MC) * TILE_B;                \
        unsigned char* lk_ = sm + (P)*16384;                                      \
        unsigned char* lv_ = lk_ + 8192;                                          \
        _Pragma("unroll")                                                         \
        for (int t_ = 0; t_ < 2; ++t_) {                                          \
            int seg_ = wv*2 + t_;                                                 \
            __builtin_amdgcn_global_load_lds((const AS1 u32*)(kt_ + seg_*1024 + L*16), \
                                             (AS3 u32*)(lk_ + seg_*1024), 16, 0, 0);   \
            __builtin_amdgcn_global_load_lds((const AS1 u32*)(vt_ + seg_*1024 + L*16), \
                                             (AS3 u32*)(lv_ + seg_*1024), 16, 0, 0);   \
        }                                                                         \
    }

    ISSUE_KV(0, 0)
    Q_PROLOGUE(Qt)

    f32x4 oacc[2][4] = {};
    float lsum[2] = {0.f, 0.f};

    for (int mc = 0; mc < NCH; ++mc) {
        const int p = mc & 1;
        __syncthreads();                       // DMA(mc) landed; buf p^1 reads done
        if (mc + 1 < NCH) ISSUE_KV(mc + 1, p ^ 1)
        const unsigned char* Ka = sm + p*16384;
        const unsigned char* Vt = Ka + 8192;
        CHUNK_COMPUTE(Ka, Vt)
    }
    EPILOGUE()
    #undef ISSUE_KV
}

// ---------------------------------------------------------------------------
// Tier (b): K tiles DMA'd (dbuf), V staged in-kernel (R6 path), 2 barriers.
// ---------------------------------------------------------------------------
__global__ __launch_bounds__(256, 3)
void attn_ktile(const float* __restrict__ QKV,
                const float* __restrict__ q_scale,
                const float* __restrict__ q_bias,
                const unsigned char* __restrict__ ws,
                float* __restrict__ out)
{
    __shared__ __align__(16) unsigned char sm[40960]; // Kbuf0 8K|Kbuf1 8K|Vt 8K|Qt/P 16K
    COMMON_IDS()
    unsigned char* Vt = sm + 16384;
    unsigned char* Qt = sm + 24576;
    unsigned char* Pw = Qt + wv*4096;

    const unsigned char* Ktiles = ws + (size_t)((b*NH + h)*NCH) * TILE_B;

    #define ISSUE_K(MC, P)                                                        \
    {                                                                             \
        const unsigned char* kt_ = Ktiles + (size_t)(MC) * TILE_B;                \
        unsigned char* lk_ = sm + (P)*8192;                                       \
        _Pragma("unroll")                                                         \
        for (int t_ = 0; t_ < 2; ++t_) {                                          \
            int seg_ = wv*2 + t_;                                                 \
            __builtin_amdgcn_global_load_lds((const AS1 u32*)(kt_ + seg_*1024 + L*16), \
                                             (AS3 u32*)(lk_ + seg_*1024), 16, 0, 0);   \
        }                                                                         \
    }
    float vv[16];
    #define PREFETCH_V(MC)                                                        \
    {                                                                             \
        const float* gv = QKV + (size_t)(b*SEQ + (MC)*64 + wv*16) * CIN + 1536 + h*64 + L; \
        _Pragma("unroll")                                                         \
        for (int j = 0; j < 16; ++j) vv[j] = gv[(size_t)j * CIN];                 \
    }
    #define STAGE_V()                                                             \
    {                                                                             \
        half8 a0, a1;                                                             \
        _Pragma("unroll")                                                         \
        for (int j = 0; j < 8; ++j) { a0[j] = (_Float16)vv[j]; a1[j] = (_Float16)vv[j+8]; } \
        *(half8*)(Vt + L*128 + (((2*wv+0) ^ (L & 7)) * 16)) = a0;                 \
        *(half8*)(Vt + L*128 + (((2*wv+1) ^ (L & 7)) * 16)) = a1;                 \
    }

    PREFETCH_V(0)
    ISSUE_K(0, 0)
    Q_PROLOGUE(Qt)

    f32x4 oacc[2][4] = {};
    float lsum[2] = {0.f, 0.f};

    for (int mc = 0; mc < NCH; ++mc) {
        const int p = mc & 1;
        __syncthreads();                    // K-DMA(mc) landed; prev Vt reads done
        STAGE_V()
        __syncthreads();                    // Vt visible
        if (mc + 1 < NCH) { ISSUE_K(mc + 1, p ^ 1) PREFETCH_V(mc + 1) }
        const unsigned char* Ka = sm + p*8192;
        CHUNK_COMPUTE(Ka, Vt)
    }
    EPILOGUE()
    #undef ISSUE_K
    #undef PREFETCH_V
    #undef STAGE_V
}

// ---------------------------------------------------------------------------
// Tier (c) fallback: exact R6 fused kernel (validated, 184 us dispatch).
// ---------------------------------------------------------------------------
__global__ __launch_bounds__(256, 3)
void fused_fallback(const float* __restrict__ QKV,
                    const float* __restrict__ q_scale,
                    const float* __restrict__ q_bias,
                    const float* __restrict__ k_scale,
                    const float* __restrict__ k_bias,
                    float* __restrict__ out)
{
    __shared__ __align__(16) unsigned char sm[32768];
    COMMON_IDS()
    unsigned char* Ka = sm;
    unsigned char* Vt = sm + 8192;
    unsigned char* Qt = sm + 16384;
    unsigned char* Pw = Qt + wv*4096;

    float4 ksr[4], kbr[4];
    #pragma unroll
    for (int i = 0; i < 4; ++i) {
        ksr[i] = ((const float4*)k_scale)[c4 * 4 + i];
        kbr[i] = ((const float4*)k_bias)[c4 * 4 + i];
    }
    float4 kx[4];
    float  vv[16];
    #define PREFETCH(MC)                                                          \
    {                                                                             \
        const size_t kb4 = (size_t)(b*SEQ + (MC)*64 + wv*16 + r4) * 576 + 192 + h*16 + c4*4; \
        _Pragma("unroll")                                                         \
        for (int i = 0; i < 4; ++i) kx[i] = QKV4[kb4 + i];                        \
        const float* gv = QKV + (size_t)(b*SEQ + (MC)*64 + wv*16) * CIN + 1536 + h*64 + L; \
        _Pragma("unroll")                                                         \
        for (int j = 0; j < 16; ++j) vv[j] = gv[(size_t)j * CIN];                 \
    }
    #define STAGE_KV()                                                            \
    {                                                                             \
        const int row = wv*16 + r4;                                               \
        float s = 0.f, s2 = 0.f;                                                  \
        _Pragma("unroll")                                                         \
        for (int i = 0; i < 4; ++i) {                                             \
            s  += kx[i].x + kx[i].y + kx[i].z + kx[i].w;                          \
            s2 += kx[i].x*kx[i].x + kx[i].y*kx[i].y + kx[i].z*kx[i].z + kx[i].w*kx[i].w; \
        }                                                                         \
        s  += __shfl_xor(s, 1);  s  += __shfl_xor(s, 2);                          \
        s2 += __shfl_xor(s2, 1); s2 += __shfl_xor(s2, 2);                         \
        float mu = s * 0.015625f;                                                 \
        float rstd = rsqrtf(s2 * 0.015625f - mu*mu + 1e-6f);                      \
        float nb0 = -mu * rstd;                                                   \
        half8 h0, h1;                                                             \
        _Pragma("unroll")                                                         \
        for (int i = 0; i < 4; ++i) {                                             \
            float e0 = fmaf(kx[i].x, rstd, nb0) * ksr[i].x + kbr[i].x;            \
            float e1 = fmaf(kx[i].y, rstd, nb0) * ksr[i].y + kbr[i].y;            \
            float e2 = fmaf(kx[i].z, rstd, nb0) * ksr[i].z + kbr[i].z;            \
            float e3 = fmaf(kx[i].w, rstd, nb0) * ksr[i].w + kbr[i].w;            \
            if (i < 2) { h0[i*4+0]=(_Float16)e0; h0[i*4+1]=(_Float16)e1; h0[i*4+2]=(_Float16)e2; h0[i*4+3]=(_Float16)e3; } \
            else { int j=(i-2)*4; h1[j+0]=(_Float16)e0; h1[j+1]=(_Float16)e1; h1[j+2]=(_Float16)e2; h1[j+3]=(_Float16)e3; } \
        }                                                                         \
        *(half8*)(Ka + row*128 + (((2*c4+0) ^ (row & 7)) * 16)) = h0;             \
        *(half8*)(Ka + row*128 + (((2*c4+1) ^ (row & 7)) * 16)) = h1;             \
        half8 a0, a1;                                                             \
        _Pragma("unroll")                                                         \
        for (int j = 0; j < 8; ++j) { a0[j] = (_Float16)vv[j]; a1[j] = (_Float16)vv[j+8]; } \
        *(half8*)(Vt + L*128 + (((2*wv+0) ^ (L & 7)) * 16)) = a0;                 \
        *(half8*)(Vt + L*128 + (((2*wv+1) ^ (L & 7)) * 16)) = a1;                 \
    }

    PREFETCH(0)
    Q_PROLOGUE(Qt)

    f32x4 oacc[2][4] = {};
    float lsum[2] = {0.f, 0.f};

    for (int mc = 0; mc < NCH; ++mc) {
        __syncthreads();
        STAGE_KV()
        __syncthreads();
        if (mc + 1 < NCH) PREFETCH(mc + 1)
        CHUNK_COMPUTE(Ka, Vt)
    }
    EPILOGUE()
    #undef PREFETCH
    #undef STAGE_KV
}

extern "C" void kernel_launch(void* const* d_in, const int* in_sizes, int n_in,
                              void* d_out, int out_size, void* d_ws, size_t ws_size,
                              hipStream_t stream) {
    const float* QKV     = (const float*)d_in[0];
    const float* q_scale = (const float*)d_in[1];
    const float* q_bias  = (const float*)d_in[2];
    const float* k_scale = (const float*)d_in[3];
    const float* k_bias  = (const float*)d_in[4];
    float* out = (float*)d_out;
    unsigned char* ws = (unsigned char*)d_ws;

    const dim3 agrid(NB * NH * (SEQ / TQ));   // 768 flat, XCD-decoded inside
    if (ws_size >= WS_FULL) {
        preprocess_kernel<<<dim3(NCH, NH, NB), 256, 0, stream>>>(QKV, k_scale, k_bias, ws, 1);
        attn_full<<<agrid, 256, 0, stream>>>(QKV, q_scale, q_bias, ws, out);
    } else if (ws_size >= KT_BYTES) {
        preprocess_kernel<<<dim3(NCH, NH, NB), 256, 0, stream>>>(QKV, k_scale, k_bias, ws, 0);
        attn_ktile<<<agrid, 256, 0, stream>>>(QKV, q_scale, q_bias, ws, out);
    } else {
        fused_fallback<<<agrid, 256, 0, stream>>>(QKV, q_scale, q_bias, k_scale, k_bias, out);
    }
}